// Round 5
// baseline (350.581 us; speedup 1.0000x reference)
//
#include <hip/hip_runtime.h>
#include <hip/hip_bf16.h>
#include <math.h>

#define Dm 1024
#define Tm 2048
#define Bm 2
#define Hm 16
#define HDm 64
#define Rm (Bm*Tm)   // 4096 rows
#define QS 3072      // qkv row stride (q|k|v concatenated)

typedef __attribute__((ext_vector_type(8))) short sh8;    // 8 bf16 (4 VGPRs)
typedef __attribute__((ext_vector_type(4))) float f32x4;  // MFMA C/D frag

#define AS1(p) ((const __attribute__((address_space(1))) void*)(p))
#define AS3(p) ((__attribute__((address_space(3))) void*)(p))

// fp32 -> bf16 bits, round-to-nearest-even
__device__ __forceinline__ short f2bs(float f) {
    union { float f; unsigned u; } v; v.f = f;
    unsigned r = v.u + 0x7FFFu + ((v.u >> 16) & 1u);
    return (short)(r >> 16);
}

__device__ __forceinline__ float fexp2(float x) {
#if __has_builtin(__builtin_amdgcn_exp2f)
    return __builtin_amdgcn_exp2f(x);
#else
    return exp2f(x);
#endif
}

// ---------------- weight convert: wq,wk,wv -> wqkv (bf16), wo -> wob ----
__global__ __launch_bounds__(256) void convert_w(const float* __restrict__ wq,
                                                 const float* __restrict__ wk,
                                                 const float* __restrict__ wv,
                                                 const float* __restrict__ wo,
                                                 short* __restrict__ wqkv,
                                                 short* __restrict__ wob) {
    int idx = (blockIdx.x * 256 + threadIdx.x) * 4;   // 4 elems/thread, 4M total
    const int M1 = 1 << 20;
    const float* src; short* dst; int off;
    if (idx < M1)           { src = wq; dst = wqkv;          off = idx; }
    else if (idx < 2*M1)    { src = wk; dst = wqkv + M1;     off = idx - M1; }
    else if (idx < 3*M1)    { src = wv; dst = wqkv + 2*M1;   off = idx - 2*M1; }
    else                    { src = wo; dst = wob;           off = idx - 3*M1; }
    float4 v = *(const float4*)(src + off);
    short4 o;
    o.x = f2bs(v.x); o.y = f2bs(v.y); o.z = f2bs(v.z); o.w = f2bs(v.w);
    *(short4*)(dst + off) = o;
}

// ---------------- LayerNorm: one block (256 thr) per row, bf16 out ------
__global__ __launch_bounds__(256) void ln_kernel(const float* __restrict__ x,
                                                 const float* __restrict__ scale,
                                                 short* __restrict__ out) {
    int row = blockIdx.x;
    int t = threadIdx.x;
    const float4* xr = (const float4*)(x + (size_t)row * Dm);
    float4 v = xr[t];
    float s  = v.x + v.y + v.z + v.w;
    float ss = v.x*v.x + v.y*v.y + v.z*v.z + v.w*v.w;
    #pragma unroll
    for (int off = 32; off; off >>= 1) {
        s  += __shfl_xor(s, off);
        ss += __shfl_xor(ss, off);
    }
    __shared__ float red[8];
    int wave = t >> 6, lane = t & 63;
    if (lane == 0) { red[wave*2] = s; red[wave*2+1] = ss; }
    __syncthreads();
    s  = red[0] + red[2] + red[4] + red[6];
    ss = red[1] + red[3] + red[5] + red[7];
    float mean = s * (1.0f / Dm);
    float var  = ss * (1.0f / Dm) - mean * mean;
    float rstd = 1.0f / sqrtf(var + 1e-5f);
    float4 sc = ((const float4*)scale)[t];
    short4 o;
    o.x = f2bs(sc.x * ((v.x - mean) * rstd) + sc.x);
    o.y = f2bs(sc.y * ((v.y - mean) * rstd) + sc.y);
    o.z = f2bs(sc.z * ((v.z - mean) * rstd) + sc.z);
    o.w = f2bs(sc.w * ((v.w - mean) * rstd) + sc.w);
    ((short4*)(out + (size_t)row * Dm))[t] = o;
}

// ---------------- MFMA GEMM (m97 structure): C = A @ B^T ----------------
// qsc: applied to output when BF16OUT and n0 < Dm (q-section pre-scale for
// softmax: folds 0.125*log2e so attention can use raw exp2).
template<int BN, bool BF16OUT>
__global__ __launch_bounds__(256) void gemm_mfma(const short* __restrict__ A,
                                                 const short* __restrict__ B,
                                                 const float* __restrict__ bias,
                                                 const float* __restrict__ res,
                                                 void* __restrict__ Cv,
                                                 int M, int N, int K, float qsc) {
    __shared__ short As[128*32];
    __shared__ short Bs[BN*32];
    const int NJ = BN / 32;            // 16x16 j-tiles per wave
    int t = threadIdx.x;
    int lane = t & 63, w = t >> 6;
    int l = lane & 15, quad = lane >> 4;
    int wm = (w & 1) * 64, wn = (w >> 1) * (BN/2);
    int m0 = blockIdx.y * 128, n0 = blockIdx.x * BN;

    f32x4 acc[4][NJ];
    #pragma unroll
    for (int i = 0; i < 4; i++)
        #pragma unroll
        for (int j = 0; j < NJ; j++)
            acc[i][j] = (f32x4){0.f,0.f,0.f,0.f};

    for (int k0 = 0; k0 < K; k0 += 32) {
        __syncthreads();
        #pragma unroll
        for (int p = 0; p < 2; p++) {            // A tile: 128 rows
            int off = p*4096 + t*16;             // LDS byte offset
            int row = off >> 6;
            int c = ((off >> 4) & 3) ^ (row & 3);
            const short* ga = A + (size_t)(m0 + row) * K + k0 + c*8;
            __builtin_amdgcn_global_load_lds(AS1(ga), AS3((char*)As + off), 16, 0, 0);
        }
        #pragma unroll
        for (int p = 0; p < BN/64; p++) {        // B tile: BN rows
            int off = p*4096 + t*16;
            int row = off >> 6;
            int c = ((off >> 4) & 3) ^ (row & 3);
            const short* gb = B + (size_t)(n0 + row) * K + k0 + c*8;
            __builtin_amdgcn_global_load_lds(AS1(gb), AS3((char*)Bs + off), 16, 0, 0);
        }
        __syncthreads();
        sh8 af[4], bf[NJ];
        #pragma unroll
        for (int i = 0; i < 4; i++) {
            int m = wm + i*16 + l;
            af[i] = *(const sh8*)((const char*)As + m*64 + ((quad ^ (m & 3)) * 16));
        }
        #pragma unroll
        for (int j = 0; j < NJ; j++) {
            int n = wn + j*16 + l;
            bf[j] = *(const sh8*)((const char*)Bs + n*64 + ((quad ^ (n & 3)) * 16));
        }
        #pragma unroll
        for (int i = 0; i < 4; i++)
            #pragma unroll
            for (int j = 0; j < NJ; j++)
                acc[i][j] = __builtin_amdgcn_mfma_f32_16x16x32_bf16(af[i], bf[j], acc[i][j], 0, 0, 0);
    }
    // epilogue
    float sc = (BF16OUT && n0 < Dm) ? qsc : 1.0f;   // wave-uniform
    #pragma unroll
    for (int i = 0; i < 4; i++) {
        #pragma unroll
        for (int j = 0; j < NJ; j++) {
            #pragma unroll
            for (int r = 0; r < 4; r++) {
                int m = m0 + wm + i*16 + quad*4 + r;
                int n = n0 + wn + j*16 + l;
                float vv = acc[i][j][r];
                if (BF16OUT) {
                    ((short*)Cv)[(size_t)m * N + n] = f2bs(vv * sc);
                } else {
                    vv += bias[n] + res[(size_t)m * N + n];
                    ((float*)Cv)[(size_t)m * N + n] = vv;
                }
            }
        }
    }
}

// ---------------- V transpose: qkv v-section -> vT[bh][64][2048] --------
__global__ __launch_bounds__(256) void transpose_v(const short* __restrict__ qkv,
                                                   short* __restrict__ vT) {
    __shared__ short Tl[64][72];
    int bh = blockIdx.y;               // 0..31
    int b = bh >> 4, h = bh & 15;
    int t0 = blockIdx.x * 64;
    int tid = threadIdx.x;
    int tt = tid >> 2, dg = tid & 3;   // row t, 16-dim group
    const short* src = qkv + ((size_t)(b*Tm + t0 + tt)) * QS + 2*Dm + h*HDm + dg*16;
    *(sh8*)&Tl[tt][dg*16]     = *(const sh8*)src;
    *(sh8*)&Tl[tt][dg*16 + 8] = *(const sh8*)(src + 8);
    __syncthreads();
    #pragma unroll
    for (int ph = 0; ph < 2; ph++) {
        int d = (tid >> 3) + ph*32;
        int c = tid & 7;
        sh8 o;
        #pragma unroll
        for (int j = 0; j < 8; j++) o[j] = Tl[c*8 + j][d];
        *(sh8*)(vT + ((size_t)bh*HDm + d)*Tm + t0 + c*8) = o;
    }
}

// ---------------- MFMA flash attention, S^T, no max, l via MFMA ---------
// Q pre-scaled by 0.125*log2e => p = exp2(S) raw (scores bounded, no overflow).
// S^T = K Q^T (C row = key, col = q): masks are per-register, P store packed.
// l = P @ ones via MFMA with constant all-ones B operand (each lane's C col
// holds its own row-sum). Grid (32,32) unpaired, longest-first.
__global__ __launch_bounds__(256) void attn_mfma(const short* __restrict__ qkv,
                                                 const short* __restrict__ vT,
                                                 short* __restrict__ ctx) {
    __shared__ short Kl[64*64];        // XOR-swizzled 16B chunks, row=key
    __shared__ short Vl[64*64];        // XOR-swizzled, row=dim, col=key
    __shared__ short Pl[4][16*72];     // per-wave P bounce, row=q
    int t = threadIdx.x;
    int lane = t & 63, w = t >> 6;
    int l = lane & 15, quad = lane >> 4;
    int qt = 31 - blockIdx.x;          // longest blocks dispatch first
    int bh = blockIdx.y;
    int b = bh >> 4, h = bh & 15;
    int qtbase = qt * 64;
    size_t rbase = (size_t)b * Tm;
    const short* qp0 = qkv + rbase * QS + h*HDm;
    const short* kp0 = qp0 + Dm;
    const short* vt0 = vT + (size_t)bh * HDm * Tm;

    // Q fragments (B-operand): qf[s] = Q[q=l][dim s*32 + quad*8 + j]
    sh8 qf0, qf1;
    {
        const short* qp = qp0 + (size_t)(qtbase + w*16 + l) * QS + quad*8;
        qf0 = *(const sh8*)qp;
        qf1 = *(const sh8*)(qp + 32);
    }
    const short oneb = 0x3F80;         // bf16 1.0
    sh8 ones = {oneb, oneb, oneb, oneb, oneb, oneb, oneb, oneb};

    f32x4 O[4] = {{0,0,0,0},{0,0,0,0},{0,0,0,0},{0,0,0,0}};
    f32x4 L = {0,0,0,0};
    int qrow = qtbase + w*16 + l;

    for (int kc = 0; kc <= qt; kc++) {
        int kbase = kc * 64;
        __syncthreads();
        // ---- stage K chunk (row=key, 128 B rows = 8 chunks, XOR swizzle) ----
        #pragma unroll
        for (int p = 0; p < 2; p++) {
            int off = p*4096 + t*16;
            int row = off >> 7;
            int c = ((off >> 4) & 7) ^ (row & 7);
            const short* g = kp0 + (size_t)(kbase + row) * QS + c*8;
            __builtin_amdgcn_global_load_lds(AS1(g), AS3((char*)Kl + off), 16, 0, 0);
        }
        // ---- stage V chunk from vT (row=dim, cols=keys) ----
        #pragma unroll
        for (int p = 0; p < 2; p++) {
            int off = p*4096 + t*16;
            int row = off >> 7;
            int c = ((off >> 4) & 7) ^ (row & 7);
            const short* g = vt0 + (size_t)row * Tm + kbase + c*8;
            __builtin_amdgcn_global_load_lds(AS1(g), AS3((char*)Vl + off), 16, 0, 0);
        }
        __syncthreads();

        // ---- S^T = K Q^T : S[kt] row=key(quad*4+r), col=q(l) ----
        f32x4 S[4];
        #pragma unroll
        for (int kt = 0; kt < 4; kt++) {
            const f32x4 z = {0.f,0.f,0.f,0.f};
            int key = kt*16 + l;
            const char* kb = (const char*)Kl + key*128;
            int sw = key & 7;
            sh8 k0 = *(const sh8*)(kb + ((quad ^ sw) * 16));
            sh8 k1 = *(const sh8*)(kb + (((4 + quad) ^ sw) * 16));
            f32x4 s = __builtin_amdgcn_mfma_f32_16x16x32_bf16(k0, qf0, z, 0, 0, 0);
            s = __builtin_amdgcn_mfma_f32_16x16x32_bf16(k1, qf1, s, 0, 0, 0);
            S[kt] = s;
        }
        // ---- p = exp2(s) (Q pre-scaled), mask, pack to Pl ----
        bool needmask = (kbase + 63 > qtbase + w*16);
        #pragma unroll
        for (int kt = 0; kt < 4; kt++) {
            float p[4];
            if (needmask) {
                #pragma unroll
                for (int r = 0; r < 4; r++) {
                    int key = kbase + kt*16 + quad*4 + r;
                    p[r] = (key > qrow) ? 0.f : fexp2(S[kt][r]);
                }
            } else {
                #pragma unroll
                for (int r = 0; r < 4; r++) p[r] = fexp2(S[kt][r]);
            }
            __hip_bfloat162 pa = __float22bfloat162_rn({p[0], p[1]});
            __hip_bfloat162 pb = __float22bfloat162_rn({p[2], p[3]});
            union { __hip_bfloat162 h[2]; short4 s4; } u;
            u.h[0] = pa; u.h[1] = pb;
            *(short4*)&Pl[w][l*72 + kt*16 + quad*4] = u.s4;
        }
        // ---- P A-frags (same-wave LDS round trip) ----
        sh8 p0 = *(const sh8*)&Pl[w][l*72 + quad*8];
        sh8 p1 = *(const sh8*)&Pl[w][l*72 + 32 + quad*8];
        // ---- O += P V ; L += P @ ones ----
        #pragma unroll
        for (int dt = 0; dt < 4; dt++) {
            int row = dt*16 + l;
            const char* vb = (const char*)Vl + row*128;
            int sw = row & 7;
            sh8 v0 = *(const sh8*)(vb + ((quad ^ sw) * 16));
            sh8 v1 = *(const sh8*)(vb + (((4 + quad) ^ sw) * 16));
            O[dt] = __builtin_amdgcn_mfma_f32_16x16x32_bf16(p0, v0, O[dt], 0, 0, 0);
            O[dt] = __builtin_amdgcn_mfma_f32_16x16x32_bf16(p1, v1, O[dt], 0, 0, 0);
        }
        L = __builtin_amdgcn_mfma_f32_16x16x32_bf16(p0, ones, L, 0, 0, 0);
        L = __builtin_amdgcn_mfma_f32_16x16x32_bf16(p1, ones, L, 0, 0, 0);
    }
    // ---- epilogue: each lane owns its l in L[r]; normalize, store ----
    #pragma unroll
    for (int r = 0; r < 4; r++) {
        float inv = 1.0f / L[r];
        int row = qtbase + w*16 + quad*4 + r;
        #pragma unroll
        for (int dt = 0; dt < 4; dt++)
            ctx[(rbase + row) * Dm + h*HDm + dt*16 + l] = f2bs(O[dt][r] * inv);
    }
}

// ---------------- launch ----------------
extern "C" void kernel_launch(void* const* d_in, const int* in_sizes, int n_in,
                              void* d_out, int out_size, void* d_ws, size_t ws_size,
                              hipStream_t stream) {
    const float* x   = (const float*)d_in[0];
    const float* wq  = (const float*)d_in[1];
    const float* wk  = (const float*)d_in[2];
    const float* wv  = (const float*)d_in[3];
    const float* wo  = (const float*)d_in[4];
    const float* bo  = (const float*)d_in[5];
    const float* ln1 = (const float*)d_in[6];
    const float* ln2 = (const float*)d_in[7];
    float* out = (float*)d_out;

    short* lnb  = (short*)d_ws;              // 4096*1024 (aliased by vT)
    short* vT   = lnb;                       // lnb dead after qkv GEMM
    short* ctxb = lnb + (size_t)Rm*Dm;       // 4096*1024
    short* qkv  = ctxb + (size_t)Rm*Dm;      // 4096*3072
    short* wqkv = qkv + (size_t)Rm*QS;       // 3072*1024
    short* wob  = wqkv + (size_t)3*Dm*Dm;    // 1024*1024

    const float qsc = 0.125f * 1.44269504f;  // fold /sqrt(hd) and log2e into Q

    dim3 qgrid(QS/128, Rm/128);   // (24, 32)
    dim3 pgrid(Dm/64,  Rm/128);   // (16, 32)
    dim3 agrid(32, Bm*Hm);        // (qt, bh) = (32, 32)
    dim3 tgrid(Tm/64, Bm*Hm);     // (32, 32)

    convert_w<<<4096, 256, 0, stream>>>(wq, wk, wv, wo, wqkv, wob);

    // ---- Block 1 ----
    ln_kernel<<<Rm, 256, 0, stream>>>(x, ln1, lnb);
    gemm_mfma<128, true><<<qgrid, 256, 0, stream>>>(lnb, wqkv, nullptr, nullptr, qkv, Rm, QS, Dm, qsc);
    transpose_v<<<tgrid, 256, 0, stream>>>(qkv, vT);
    attn_mfma<<<agrid, 256, 0, stream>>>(qkv, vT, ctxb);
    gemm_mfma<64, false><<<pgrid, 256, 0, stream>>>(ctxb, wob, bo, x, out, Rm, Dm, Dm, 1.0f);

    // ---- Block 2 (same weights, ln2) ----
    ln_kernel<<<Rm, 256, 0, stream>>>(out, ln2, lnb);
    gemm_mfma<128, true><<<qgrid, 256, 0, stream>>>(lnb, wqkv, nullptr, nullptr, qkv, Rm, QS, Dm, qsc);
    transpose_v<<<tgrid, 256, 0, stream>>>(qkv, vT);
    attn_mfma<<<agrid, 256, 0, stream>>>(qkv, vT, ctxb);
    gemm_mfma<64, false><<<pgrid, 256, 0, stream>>>(ctxb, wob, bo, out, out, Rm, Dm, Dm, 1.0f);
}